// Round 13
// baseline (478.005 us; speedup 1.0000x reference)
//
#include <hip/hip_runtime.h>

// ---------------------------------------------------------------------------
// AttentionGrowingModule: out = X + (softmax((X Wq + bq)(X Wk + bk)^T / sqrt(128)) (X Wv + bv)) Wo + bo
// B=8, S=2048, D_E=1024, D_K=D_V=128.
// Inputs fp32; OUTPUT fp32 (round-9 analysis: harness "(bf16" label is literal
// text; reference output is jnp.float32 -> d_out is float*).  Internals: bf16
// MFMA, fp32 accum.  Q,K,V bf16 staged in d_out (12 MB of 67; proj rewrites
// all of out afterwards, stream-ordered).  H bf16 in d_ws (4 MB).
// ---------------------------------------------------------------------------

typedef __attribute__((ext_vector_type(8))) short bf8_t;   // 8 bf16 = 4 VGPRs
typedef __attribute__((ext_vector_type(4))) float f4_t;    // mfma 16x16 accum

#define MFMA(a, b, c) __builtin_amdgcn_mfma_f32_16x16x32_bf16((a), (b), (c), 0, 0, 0)

__device__ __forceinline__ float bf2f(ushort h) {
    return __uint_as_float(((uint)h) << 16);
}
__device__ __forceinline__ ushort f2bf(float f) {
    uint u = __float_as_uint(f);
    u += 0x7fff + ((u >> 16) & 1);   // round-to-nearest-even
    return (ushort)(u >> 16);
}
__device__ __forceinline__ uint pk2(float a, float b) {
    return (uint)f2bf(a) | ((uint)f2bf(b) << 16);
}

// ---------------------------------------------------------------------------
// Kernel 1: QKV projection (MFMA).  M tile 64 (4 waves x 16), N = 128, K step 32.
// Layouts (guide §3): A: m=lane&15, k-slots 8*(lane>>4)+e; B: n=lane&15
// (staged transposed Ws[n][k]); D: col=lane&15, row=4*(lane>>4)+reg.
// A/B use the same k-slot convention -> correct for any HW k permutation.
// ---------------------------------------------------------------------------
__global__ __launch_bounds__(256) void qkv_kernel(
    const float* __restrict__ X,
    const float* __restrict__ Wq, const float* __restrict__ bq,
    const float* __restrict__ Wk, const float* __restrict__ bk,
    const float* __restrict__ Wv, const float* __restrict__ bv,
    ushort* __restrict__ Qo, ushort* __restrict__ Ko, ushort* __restrict__ Vo)
{
    const int which = blockIdx.y;
    const float* W    = (which == 0) ? Wq : (which == 1) ? Wk : Wv;
    const float* bias = (which == 0) ? bq : (which == 1) ? bk : bv;
    ushort* Out       = (which == 0) ? Qo : (which == 1) ? Ko : Vo;

    __shared__ __align__(16) ushort Xs[64][40];
    __shared__ __align__(16) ushort Ws[128][40];

    const int tid  = threadIdx.x;
    const int lane = tid & 63;
    const int w    = tid >> 6;
    const int g    = lane >> 4;
    const int ln   = lane & 15;
    const int m0   = blockIdx.x * 64;

    f4_t acc[8];
#pragma unroll
    for (int i = 0; i < 8; i++) acc[i] = (f4_t)(0.f);

    for (int k0 = 0; k0 < 1024; k0 += 32) {
        __syncthreads();
        {
            int r = tid >> 2, c0 = (tid & 3) * 8;
            const float* src = &X[(size_t)(m0 + r) * 1024 + k0 + c0];
            float4 v0 = *(const float4*)&src[0];
            float4 v1 = *(const float4*)&src[4];
            uint4 wv;
            wv.x = pk2(v0.x, v0.y); wv.y = pk2(v0.z, v0.w);
            wv.z = pk2(v1.x, v1.y); wv.w = pk2(v1.z, v1.w);
            *(uint4*)&Xs[r][c0] = wv;
        }
        {
            int kk = tid >> 3, a = tid & 7, n0a = a * 16;
            const float* src = &W[(size_t)(k0 + kk) * 128 + n0a];
            float tmp[16];
#pragma unroll
            for (int j = 0; j < 16; j += 4)
                *(float4*)&tmp[j] = *(const float4*)&src[j];
#pragma unroll
            for (int jj = 0; jj < 16; jj++) {
                int j = (jj + 2 * a) & 15;   // rotate write order to spread banks
                Ws[n0a + j][kk] = f2bf(tmp[j]);
            }
        }
        __syncthreads();

        bf8_t a = *(const bf8_t*)&Xs[16 * w + ln][8 * g];
#pragma unroll
        for (int nt = 0; nt < 8; nt++) {
            bf8_t b = *(const bf8_t*)&Ws[nt * 16 + ln][8 * g];
            acc[nt] = MFMA(a, b, acc[nt]);
        }
    }

#pragma unroll
    for (int nt = 0; nt < 8; nt++) {
        float bb = bias[nt * 16 + ln];
#pragma unroll
        for (int r = 0; r < 4; r++) {
            int row = m0 + 16 * w + 4 * g + r;
            Out[(size_t)row * 128 + nt * 16 + ln] = f2bf(acc[nt][r] + bb);
        }
    }
}

// ---------------------------------------------------------------------------
// Kernel 2: flash attention (MFMA, bf16).  Per block: one batch, 64 q-rows
// (4 waves x 16).  KV tiles of 32.  Swapped QK^T: S^T[t][q] = K[t][:]·Q[q][:];
// softmax reduce over t in-lane (8 regs) + shfl_xor(16,32).  P^T -> P
// A-fragment via per-wave LDS round-trip (Pl).
// ---------------------------------------------------------------------------
__global__ __launch_bounds__(256) void attn_kernel(
    const ushort* __restrict__ Qg, const ushort* __restrict__ Kg,
    const ushort* __restrict__ Vg, ushort* __restrict__ Hg)
{
    __shared__ __align__(16) ushort Ks[32][136];
    __shared__ __align__(16) ushort Vt[128][40];   // V transposed: Vt[d][t]
    __shared__ __align__(16) ushort Pl[4][16][40]; // per-wave P[q][t]

    const int tid  = threadIdx.x;
    const int lane = tid & 63;
    const int w    = tid >> 6;
    const int g    = lane >> 4;
    const int ln   = lane & 15;
    const int b    = blockIdx.y;
    const int q0   = blockIdx.x * 64 + 16 * w;
    const size_t base = (size_t)b * 2048 * 128;

    // Q fragments (B-operand of S^T mfma): lane holds Q[q=ln][d=32s+8g+e]
    bf8_t qf[4];
#pragma unroll
    for (int s = 0; s < 4; s++)
        qf[s] = *(const bf8_t*)&Qg[base + (size_t)(q0 + ln) * 128 + 32 * s + 8 * g];

    f4_t O[8];
#pragma unroll
    for (int i = 0; i < 8; i++) O[i] = (f4_t)(0.f);
    float m_run = -INFINITY, l_run = 0.f;
    const float rscale = 0.0883883476483184f;  // 1/sqrt(128)

    for (int t0 = 0; t0 < 2048; t0 += 32) {
        __syncthreads();
        // stage K tile 32x128 (row-major bf16)
        {
            int r = tid >> 3, c0 = (tid & 7) * 16;
            const ushort* src = &Kg[base + (size_t)(t0 + r) * 128 + c0];
            *(uint4*)&Ks[r][c0]     = *(const uint4*)&src[0];
            *(uint4*)&Ks[r][c0 + 8] = *(const uint4*)&src[8];
        }
        // stage V^T tile 128x32
        {
            int r = tid >> 3, a = tid & 7, c0 = a * 16;
            const ushort* src = &Vg[base + (size_t)(t0 + r) * 128 + c0];
            ushort tmp[16];
            *(uint4*)&tmp[0] = *(const uint4*)&src[0];
            *(uint4*)&tmp[8] = *(const uint4*)&src[8];
#pragma unroll
            for (int jj = 0; jj < 16; jj++) {
                int j = (jj + 2 * a) & 15;
                Vt[c0 + j][r] = tmp[j];
            }
        }
        __syncthreads();

        // S^T = K * Q^T, two 16-row half-tiles
        f4_t st[2];
#pragma unroll
        for (int h = 0; h < 2; h++) {
            f4_t a = (f4_t)(0.f);
#pragma unroll
            for (int s = 0; s < 4; s++) {
                bf8_t kf = *(const bf8_t*)&Ks[16 * h + ln][32 * s + 8 * g];
                a = MFMA(kf, qf[s], a);
            }
            st[h] = a * rscale;
        }
        // lane holds S^T[t_local = 4g+r (+16h)][q = ln]

        // online softmax over t (per q = ln)
        float mx = fmaxf(fmaxf(st[0][0], st[0][1]), fmaxf(st[0][2], st[0][3]));
        mx = fmaxf(mx, fmaxf(fmaxf(st[1][0], st[1][1]), fmaxf(st[1][2], st[1][3])));
        mx = fmaxf(mx, __shfl_xor(mx, 16));
        mx = fmaxf(mx, __shfl_xor(mx, 32));
        float m_new = fmaxf(m_run, mx);
        float alpha = __expf(m_run - m_new);   // first iter: exp(-inf)=0
        float p[8];
        float rsum = 0.f;
#pragma unroll
        for (int r = 0; r < 4; r++) { p[r]     = __expf(st[0][r] - m_new); rsum += p[r]; }
#pragma unroll
        for (int r = 0; r < 4; r++) { p[4 + r] = __expf(st[1][r] - m_new); rsum += p[4 + r]; }
        rsum += __shfl_xor(rsum, 16);
        rsum += __shfl_xor(rsum, 32);
        l_run = l_run * alpha + rsum;
        m_run = m_new;

        // rescale O (accumulator rows are q_local = 4g+r; alpha lives at lane q)
        float ar[4];
#pragma unroll
        for (int r = 0; r < 4; r++) ar[r] = __shfl(alpha, 4 * g + r);
#pragma unroll
        for (int nt = 0; nt < 8; nt++)
#pragma unroll
            for (int r = 0; r < 4; r++) O[nt][r] *= ar[r];

        // P^T -> P A-fragment via per-wave LDS round-trip.
#pragma unroll
        for (int j = 0; j < 4; j++) {
            Pl[w][ln][4 * g + j]      = f2bf(p[j]);
            Pl[w][ln][16 + 4 * g + j] = f2bf(p[4 + j]);
        }
        // lane (g,ln) reads P[q=ln][t=8g..8g+7]; within-wave RAW (lockstep + waitcnt)
        bf8_t af = *(const bf8_t*)&Pl[w][ln][8 * g];

        // PV: O[q][d] += P[q][t] V[t][d]
#pragma unroll
        for (int nt = 0; nt < 8; nt++) {
            bf8_t vf = *(const bf8_t*)&Vt[nt * 16 + ln][8 * g];
            O[nt] = MFMA(af, vf, O[nt]);
        }
    }

    // epilogue: H = O / l
    float inv = 1.0f / l_run;  // valid for q = ln
    float ir[4];
#pragma unroll
    for (int r = 0; r < 4; r++) ir[r] = __shfl(inv, 4 * g + r);
#pragma unroll
    for (int nt = 0; nt < 8; nt++)
#pragma unroll
        for (int r = 0; r < 4; r++) {
            Hg[base + (size_t)(q0 + 4 * g + r) * 128 + nt * 16 + ln] =
                f2bf(O[nt][r] * ir[r]);
        }
}

// ---------------------------------------------------------------------------
// Kernel 3: out = X + H * Wo + bo (fp32 OUT).  M tile 64, N tile 128, K = 128.
// ---------------------------------------------------------------------------
__global__ __launch_bounds__(256) void proj_kernel(
    const ushort* __restrict__ Hg, const float* __restrict__ Wo,
    const float* __restrict__ bo, const float* __restrict__ Xg,
    float* __restrict__ Out)
{
    __shared__ __align__(16) ushort Hs[64][136];
    __shared__ __align__(16) ushort Wt[128][136];

    const int tid  = threadIdx.x;
    const int lane = tid & 63;
    const int w    = tid >> 6;
    const int g    = lane >> 4;
    const int ln   = lane & 15;
    const int m0   = blockIdx.x * 64;
    const int n0   = blockIdx.y * 128;

    {
        int r = tid >> 2, c0 = (tid & 3) * 32;
#pragma unroll
        for (int cc = 0; cc < 32; cc += 8)
            *(uint4*)&Hs[r][c0 + cc] =
                *(const uint4*)&Hg[(size_t)(m0 + r) * 128 + c0 + cc];
    }
    {
        int k = tid >> 1, half = (tid & 1) * 64;
        const float* src = &Wo[(size_t)k * 1024 + n0 + half];
#pragma unroll
        for (int j0 = 0; j0 < 64; j0 += 4) {
            float4 t4 = *(const float4*)&src[j0];
            Wt[half + j0 + 0][k] = f2bf(t4.x);
            Wt[half + j0 + 1][k] = f2bf(t4.y);
            Wt[half + j0 + 2][k] = f2bf(t4.z);
            Wt[half + j0 + 3][k] = f2bf(t4.w);
        }
    }
    __syncthreads();

    f4_t acc[8];
#pragma unroll
    for (int i = 0; i < 8; i++) acc[i] = (f4_t)(0.f);
#pragma unroll
    for (int s = 0; s < 4; s++) {
        bf8_t a = *(const bf8_t*)&Hs[16 * w + ln][32 * s + 8 * g];
#pragma unroll
        for (int nt = 0; nt < 8; nt++) {
            bf8_t bfr = *(const bf8_t*)&Wt[nt * 16 + ln][32 * s + 8 * g];
            acc[nt] = MFMA(a, bfr, acc[nt]);
        }
    }

#pragma unroll
    for (int nt = 0; nt < 8; nt++) {
        float bb = bo[n0 + nt * 16 + ln];
#pragma unroll
        for (int r = 0; r < 4; r++) {
            size_t idx = (size_t)(m0 + 16 * w + 4 * g + r) * 1024 + n0 + nt * 16 + ln;
            Out[idx] = acc[nt][r] + bb + Xg[idx];   // fp32 output
        }
    }
}

// ---------------------------------------------------------------------------
extern "C" void kernel_launch(void* const* d_in, const int* in_sizes, int n_in,
                              void* d_out, int out_size, void* d_ws, size_t ws_size,
                              hipStream_t stream)
{
    const float* X  = (const float*)d_in[0];
    const float* Wq = (const float*)d_in[1];
    const float* bq = (const float*)d_in[2];
    const float* Wk = (const float*)d_in[3];
    const float* bk = (const float*)d_in[4];
    const float* Wv = (const float*)d_in[5];
    const float* bv = (const float*)d_in[6];
    const float* Wo = (const float*)d_in[7];
    const float* bo = (const float*)d_in[8];
    float* out = (float*)d_out;   // fp32 output (16.7M floats = 67 MB)

    const size_t NR = (size_t)8 * 2048;       // 16384 rows
    // Q,K,V bf16 staged in the first 12 MB of d_out; proj rewrites all of out
    // afterwards (stream-ordered).  H bf16 in d_ws (4 MB).
    ushort* Q = (ushort*)d_out;
    ushort* K = Q + NR * 128;
    ushort* V = K + NR * 128;
    ushort* H = (ushort*)d_ws;

    qkv_kernel<<<dim3(256, 3), 256, 0, stream>>>(X, Wq, bq, Wk, bk, Wv, bv, Q, K, V);
    attn_kernel<<<dim3(32, 8), 256, 0, stream>>>(Q, K, V, H);
    proj_kernel<<<dim3(256, 8), 256, 0, stream>>>(H, Wo, bo, X, out);
}